// Round 3
// baseline (321.234 us; speedup 1.0000x reference)
//
#include <hip/hip_runtime.h>
#include <stdint.h>

#define N_NODES 50000
#define N_EDGES 800000
#define IN_C 64
#define HID 128
#define OUT_C 2
#define N_GRAPHS 64
#define NBUCK 196                    // ceil(N_NODES/256) buckets of 256 nodes
#define BCAP 6144                    // bucket capacity (mean 4096, sd ~64)
#define ECH 4096                     // edges per phase-A block
#define PCH 128                      // nodes per k_pool2 chunk

typedef long long i64;
typedef __attribute__((ext_vector_type(8))) short bf8;    // 8 bf16 = 4 VGPRs
typedef __attribute__((ext_vector_type(4))) float f32x4;  // MFMA C/D frag

__device__ __forceinline__ float bf2f(ushort h) {
    return __uint_as_float(((uint)h) << 16);
}
__device__ __forceinline__ ushort f2bf(float f) {
    uint x = __float_as_uint(f);
    uint r = x + 0x7fffu + ((x >> 16) & 1u);   // RNE
    return (ushort)(r >> 16);
}
__device__ __forceinline__ float loadf(const void* p, size_t i, int bf) {
    return bf ? bf2f(((const ushort*)p)[i]) : ((const float*)p)[i];
}
__device__ __forceinline__ int clampi(int v, int lo, int hi) {
    return min(max(v, lo), hi);
}

__device__ __forceinline__ int edge_src(const void* ei, int e, int wide) {
    return wide ? (int)((const i64*)ei)[e] : ((const int*)ei)[e];
}
__device__ __forceinline__ int edge_dst(const void* ei, int e, int wide) {
    return wide ? (int)((const i64*)ei)[N_EDGES + e] : ((const int*)ei)[N_EDGES + e];
}
__device__ __forceinline__ i64 batch_at(const void* b, int i, int wide) {
    return wide ? ((const i64*)b)[i] : (i64)((const int*)b)[i];
}

// unpack a uint4 (8 bf16) into 8 floats / accumulate
__device__ __forceinline__ void bset(float* a, uint4 u) {
    a[0] = bf2f((ushort)(u.x & 0xffffu)); a[1] = bf2f((ushort)(u.x >> 16));
    a[2] = bf2f((ushort)(u.y & 0xffffu)); a[3] = bf2f((ushort)(u.y >> 16));
    a[4] = bf2f((ushort)(u.z & 0xffffu)); a[5] = bf2f((ushort)(u.z >> 16));
    a[6] = bf2f((ushort)(u.w & 0xffffu)); a[7] = bf2f((ushort)(u.w >> 16));
}
__device__ __forceinline__ void bacc(float* a, uint4 u) {
    a[0] += bf2f((ushort)(u.x & 0xffffu)); a[1] += bf2f((ushort)(u.x >> 16));
    a[2] += bf2f((ushort)(u.y & 0xffffu)); a[3] += bf2f((ushort)(u.y >> 16));
    a[4] += bf2f((ushort)(u.z & 0xffffu)); a[5] += bf2f((ushort)(u.z >> 16));
    a[6] += bf2f((ushort)(u.w & 0xffffu)); a[7] += bf2f((ushort)(u.w >> 16));
}
__device__ __forceinline__ uint pk2(float lo, float hi) {
    return ((uint)f2bf(hi) << 16) | (uint)f2bf(lo);
}
// 8 f32 * dv -> MFMA bf16 A-fragment (8 bf16)
__device__ __forceinline__ bf8 packbf8(const float* a, float dv) {
    union { bf8 v; uint u[4]; } r;
    r.u[0] = pk2(a[0] * dv, a[1] * dv);
    r.u[1] = pk2(a[2] * dv, a[3] * dv);
    r.u[2] = pk2(a[4] * dv, a[5] * dv);
    r.u[3] = pk2(a[6] * dv, a[7] * dv);
    return r.v;
}

// ---- init: zero bcnt/gbuf/WT; block 0 also runs the dtype probes ----
__global__ __launch_bounds__(256) void k_init(const uint* __restrict__ braw,
                                              const uint* __restrict__ xraw,
                                              int* __restrict__ bcnt,
                                              float* __restrict__ gbuf,
                                              float* __restrict__ WT,
                                              int* __restrict__ iflag,
                                              int* __restrict__ fflag) {
    int i = blockIdx.x * blockDim.x + threadIdx.x;
    if (i < N_GRAPHS * HID) gbuf[i] = 0.f;
    if (i < NBUCK) bcnt[i] = 0;
    float4 z = make_float4(0.f, 0.f, 0.f, 0.f);
    for (int j = i; j < N_NODES * 16; j += gridDim.x * blockDim.x)
        ((float4*)WT)[j] = z;                       // 12.8 MB zero
    if (blockIdx.x == 0) {
        __shared__ uint si[128];
        __shared__ int sf[256];
        int t = threadIdx.x;
        if (t < 128) si[t] = (t < 100) ? braw[25001 + 2 * t] : 0u;
        uint e = (xraw[t] >> 7) & 0xFFu;
        sf[t] = (e >= 100u && e <= 140u) ? 1 : 0;
        __syncthreads();
        for (int off = 128; off > 0; off >>= 1) {
            if (t < off) {
                sf[t] += sf[t + off];
                if (off <= 64 && t < 64) si[t] |= si[t + off];
            }
            __syncthreads();
        }
        if (t == 0) {
            *iflag = (si[0] == 0u) ? 1 : 0;   // 1 = int64, 0 = int32
            *fflag = (sf[0] >= 192) ? 1 : 0;  // 1 = bf16,  0 = f32
        }
    }
}

// ---- phase A: bin edges by dst>>8 via LDS-sorted staging; contiguous runs.
// 1024 threads/block. Threads t<256 of blocks 0..31 also transpose W1. ----
__global__ __launch_bounds__(1024) void k_binA(const void* __restrict__ ei,
                                               const int* __restrict__ iflag,
                                               const int* __restrict__ fflag,
                                               const void* __restrict__ W1,
                                               ushort* __restrict__ Wt1,
                                               int* __restrict__ bcnt,
                                               uint2* __restrict__ bmem) {
    int t = threadIdx.x;
    if (t < 256 && blockIdx.x < (IN_C * HID) / 256) {
        int ff = *fflag;
        int idx = blockIdx.x * 256 + t;
        int k = idx >> 7, n = idx & 127;
        Wt1[n * IN_C + k] = f2bf(loadf(W1, idx, ff));
    }
    int wide = *iflag;
    __shared__ int cnt[NBUCK];
    __shared__ int obase[NBUCK];
    __shared__ int run[NBUCK];
    __shared__ int gbase[NBUCK];
    __shared__ int sc[256];
    __shared__ uint2 stage[ECH];
    int e0 = blockIdx.x * ECH;
    int m = min(ECH, N_EDGES - e0);
    for (int i = t; i < NBUCK; i += 1024) cnt[i] = 0;
    __syncthreads();
    for (int i = t; i < m; i += 1024) {
        int d = edge_dst(ei, e0 + i, wide);
        atomicAdd(&cnt[d >> 8], 1);
    }
    __syncthreads();
    int cv = (t < NBUCK) ? cnt[t] : 0;
    if (t < 256) sc[t] = cv;
    __syncthreads();
    for (int off = 1; off < 256; off <<= 1) {
        int v = (t >= off && t < 256) ? sc[t - off] : 0;
        __syncthreads();
        if (t < 256) sc[t] += v;
        __syncthreads();
    }
    if (t < NBUCK) {
        int ex = sc[t] - cv;
        obase[t] = ex;
        run[t] = ex;
        gbase[t] = (cv > 0) ? atomicAdd(&bcnt[t], cv) : 0;
    }
    __syncthreads();
    for (int i = t; i < m; i += 1024) {
        int s = edge_src(ei, e0 + i, wide);
        int d = edge_dst(ei, e0 + i, wide);
        int slot = atomicAdd(&run[d >> 8], 1);
        uint2 pr; pr.x = (uint)s; pr.y = (uint)d;
        stage[slot] = pr;
    }
    __syncthreads();
    for (int i = t; i < m; i += 1024) {
        uint2 pr = stage[i];
        int b = (int)(pr.y >> 8);
        int pos = gbase[b] + (i - obase[b]);
        if (pos < BCAP) bmem[(size_t)b * BCAP + pos] = pr;
    }
}

// ---- phase B: per-bucket LDS counting-sort -> offs/csr/dinv (coalesced),
// self-scans bcnt, writes Y1 = bf16(dinv * x), and builds the pooled-
// aggregation matrix WT[s][g] += dinv[d] per edge (+ self dinv[s]). ----
__global__ __launch_bounds__(1024) void k_binB(const uint2* __restrict__ bmem,
                                               const int* __restrict__ bcnt,
                                               const void* __restrict__ x,
                                               const void* __restrict__ batch,
                                               const int* __restrict__ iflag,
                                               const int* __restrict__ fflag,
                                               int* __restrict__ offs,
                                               int* __restrict__ csr,
                                               float* __restrict__ dinv,
                                               float* __restrict__ WT,
                                               ushort* __restrict__ Y1) {
    int b = blockIdx.x;
    int t = threadIdx.x;
    int node0 = b << 8;
    int wide = *iflag;
    __shared__ int sc[256];
    __shared__ int degl[256];
    __shared__ int run[256];
    __shared__ float sdinv[256];
    __shared__ int sgb[256];
    __shared__ int sbase, scnt;
    __shared__ int stage[BCAP];
    int v = (t < NBUCK) ? bcnt[t] : 0;
    if (t < 256) sc[t] = v;
    __syncthreads();
    for (int off = 1; off < 256; off <<= 1) {
        int u = (t >= off && t < 256) ? sc[t - off] : 0;
        __syncthreads();
        if (t < 256) sc[t] += u;
        __syncthreads();
    }
    if (t == b) {
        int c = clampi(v, 0, BCAP);
        scnt = c;
        sbase = clampi(sc[t] - v, 0, N_EDGES - c);
    }
    if (t < 256) degl[t] = 0;
    __syncthreads();
    int cnt = scnt;
    int base = sbase;
    for (int i = t; i < cnt; i += 1024) {
        uint2 pr = bmem[(size_t)b * BCAP + i];
        atomicAdd(&degl[pr.y & 255], 1);
    }
    __syncthreads();
    int dv = (t < 256) ? degl[t] : 0;
    if (t < 256) sc[t] = dv;
    __syncthreads();
    for (int off = 1; off < 256; off <<= 1) {
        int u = (t >= off && t < 256) ? sc[t - off] : 0;
        __syncthreads();
        if (t < 256) sc[t] += u;
        __syncthreads();
    }
    if (t < 256) {
        int ex = sc[t] - dv;
        run[t] = ex;
        float di = rsqrtf((float)(dv + 1));
        sdinv[t] = di;
        int n = node0 + t;
        if (n < N_NODES) {
            offs[n] = base + ex;
            dinv[n] = di;
            int g = clampi((int)batch_at(batch, n, wide), 0, N_GRAPHS - 1);
            sgb[t] = g;
            atomicAdd(&WT[(size_t)n * N_GRAPHS + g], di);   // self term
        } else {
            sgb[t] = 0;
        }
    }
    if (b == 0 && t == 0) offs[N_NODES] = N_EDGES;
    __syncthreads();
    for (int i = t; i < cnt; i += 1024) {
        uint2 pr = bmem[(size_t)b * BCAP + i];
        int dl = pr.y & 255;
        int slot = atomicAdd(&run[dl], 1);
        stage[clampi(slot, 0, BCAP - 1)] = (int)pr.x;
        // WT[src][graph(dst)] += dinv[dst]
        atomicAdd(&WT[(size_t)pr.x * N_GRAPHS + sgb[dl]], sdinv[dl]);
    }
    __syncthreads();
    for (int i = t; i < cnt; i += 1024) csr[base + i] = stage[i];
    int ff = *fflag;
    for (int idx = t; idx < 256 * (IN_C / 4); idx += 1024) {
        int nl = idx >> 4, c4 = (idx & 15) * 4;
        int nn = node0 + nl;
        if (nn < N_NODES) {
            float x0, x1, x2, x3;
            if (ff) {
                ushort4 u = *(const ushort4*)((const ushort*)x + (size_t)nn * IN_C + c4);
                x0 = bf2f(u.x); x1 = bf2f(u.y); x2 = bf2f(u.z); x3 = bf2f(u.w);
            } else {
                float4 vv = *(const float4*)((const float*)x + (size_t)nn * IN_C + c4);
                x0 = vv.x; x1 = vv.y; x2 = vv.z; x3 = vv.w;
            }
            float di = sdinv[nl];
            ushort4 o;
            o.x = f2bf(x0 * di); o.y = f2bf(x1 * di);
            o.z = f2bf(x2 * di); o.w = f2bf(x3 * di);
            *(ushort4*)(Y1 + (size_t)nn * IN_C + c4) = o;
        }
    }
}

// ---- fused layer 1 = gather-into-A-fragment + MFMA.
// Wave = 16 nodes. Lane (m16,q) gather-accumulates Y1 channel slices
// [q*8,+8) and [32+q*8,+8) for node rowbase+m16 directly in registers
// (exactly the MFMA A-frag layout), then h1s = relu(agg@W1+b1)*dinv. ----
__global__ __launch_bounds__(256) void k_l1(const ushort* __restrict__ Y1,
                                            const float* __restrict__ dinv,
                                            const int* __restrict__ offs,
                                            const int* __restrict__ csr,
                                            const ushort* __restrict__ Wt,
                                            const int* __restrict__ fflag,
                                            const void* __restrict__ bias,
                                            ushort* __restrict__ out) {
    int ff = *fflag;
    int wave = threadIdx.x >> 6;
    int lane = threadIdx.x & 63;
    int m16 = lane & 15;
    int q = lane >> 4;
    int rowbase = blockIdx.x * 64 + wave * 16;
    int n = min(rowbase + m16, N_NODES - 1);

    const uint4* y4 = (const uint4*)Y1;        // row = 8 uint4 (128 B)
    size_t rb = (size_t)n * 8 + q;
    float a0[8], a1[8];
    bset(a0, y4[rb]);                          // self contribution
    bset(a1, y4[rb + 4]);
    int s = offs[n];
    int e = min(offs[n + 1], s + 4096);        // poison-replay guard
    int i = s;
    for (; i + 4 <= e; i += 4) {
        uint4 u[4][2];
#pragma unroll
        for (int k = 0; k < 4; k++) {
            size_t r = (size_t)csr[i + k] * 8 + q;
            u[k][0] = y4[r];
            u[k][1] = y4[r + 4];
        }
#pragma unroll
        for (int k = 0; k < 4; k++) { bacc(a0, u[k][0]); bacc(a1, u[k][1]); }
    }
    for (; i < e; i++) {
        size_t r = (size_t)csr[i] * 8 + q;
        bacc(a0, y4[r]);
        bacc(a1, y4[r + 4]);
    }
    float dvn = dinv[n];
    bf8 af0 = packbf8(a0, dvn);
    bf8 af1 = packbf8(a1, dvn);

    f32x4 acc[8];
#pragma unroll
    for (int t = 0; t < 8; t++) acc[t] = (f32x4){0.f, 0.f, 0.f, 0.f};
#pragma unroll
    for (int t = 0; t < 8; t++) {
        bf8 b0 = *(const bf8*)(Wt + (size_t)(t * 16 + m16) * IN_C + q * 8);
        acc[t] = __builtin_amdgcn_mfma_f32_16x16x32_bf16(af0, b0, acc[t], 0, 0, 0);
        bf8 b1 = *(const bf8*)(Wt + (size_t)(t * 16 + m16) * IN_C + 32 + q * 8);
        acc[t] = __builtin_amdgcn_mfma_f32_16x16x32_bf16(af1, b1, acc[t], 0, 0, 0);
    }
    float dv[4];
    int rowok[4];
#pragma unroll
    for (int r = 0; r < 4; r++) {
        int row = rowbase + q * 4 + r;
        rowok[r] = (row < N_NODES);
        dv[r] = rowok[r] ? dinv[row] : 1.f;
    }
#pragma unroll
    for (int t = 0; t < 8; t++) {
        int col = t * 16 + m16;
        float bv = loadf(bias, col, ff);
#pragma unroll
        for (int r = 0; r < 4; r++) {
            int row = rowbase + q * 4 + r;
            if (rowok[r]) {
                float v = fmaxf(acc[t][r] + bv, 0.f) * dv[r];
                out[(size_t)row * HID + col] = f2bf(v);
            }
        }
    }
}

// ---- R19: pooled layer 2 without the gather.
// t[g][c] = sum_s WT[s][g] * h1s[s][c] — streaming outer-product over node
// chunks; register tile 4g x 8c per thread; LDS-staged WT/h1s chunks;
// atomicAdd partials into gsum (= t, pre-@W2). ----
__global__ __launch_bounds__(256) void k_pool2(const float* __restrict__ WT,
                                               const ushort* __restrict__ hs,
                                               float* __restrict__ gsum) {
    __shared__ float4 sW[PCH * 16];   // [PCH][64] f32  (32 KB)
    __shared__ uint4  sH[PCH * 16];   // [PCH][128] bf16 (32 KB)
    int t = threadIdx.x;
    int s0 = blockIdx.x * PCH;
    const float4* w4 = (const float4*)WT;   // row = 16 float4
    const uint4*  h4 = (const uint4*)hs;    // row = 16 uint4
    for (int idx = t; idx < PCH * 16; idx += 256) {
        int row = idx >> 4;
        int nn = s0 + row;
        if (nn < N_NODES) {
            sW[idx] = w4[(size_t)nn * 16 + (idx & 15)];
            sH[idx] = h4[(size_t)nn * 16 + (idx & 15)];
        } else {
            sW[idx] = make_float4(0.f, 0.f, 0.f, 0.f);
            sH[idx] = make_uint4(0u, 0u, 0u, 0u);
        }
    }
    __syncthreads();
    int tc = t & 15;        // c-block: 8*tc .. +8
    int tg = t >> 4;        // g-block: 4*tg .. +4
    float acc[4][8];
#pragma unroll
    for (int gi = 0; gi < 4; gi++)
#pragma unroll
        for (int ci = 0; ci < 8; ci++) acc[gi][ci] = 0.f;
    for (int s = 0; s < PCH; s++) {
        float4 w = sW[s * 16 + tg];
        uint4 hq = sH[s * 16 + tc];
        float h[8];
        bset(h, hq);
        float wv[4] = {w.x, w.y, w.z, w.w};
#pragma unroll
        for (int gi = 0; gi < 4; gi++) {
#pragma unroll
            for (int ci = 0; ci < 8; ci++) acc[gi][ci] += wv[gi] * h[ci];
        }
    }
    int gb = 4 * tg, cb = 8 * tc;
#pragma unroll
    for (int gi = 0; gi < 4; gi++)
#pragma unroll
        for (int ci = 0; ci < 8; ci++)
            atomicAdd(&gsum[(gb + gi) * HID + cb + ci], acc[gi][ci]);
}

// -------- MLP head: v = t[g]@W2; out = relu((v/cnt + b2)@Wm1+bm1)@Wm2+bm2 ---
__global__ void k_mlp(const float* __restrict__ gsum, const void* __restrict__ batch,
                      const int* __restrict__ iflag, const void* __restrict__ W2,
                      const void* __restrict__ b2,
                      const void* __restrict__ Wm1, const void* __restrict__ bm1,
                      const void* __restrict__ Wm2, const void* __restrict__ bm2,
                      const int* __restrict__ fflag, float* __restrict__ out) {
    int ff = *fflag;
    int wide = *iflag;
    int gr = blockIdx.x;
    int c = threadIdx.x;
    int lo = 0, hi = N_NODES;
    while (lo < hi) { int m = (lo + hi) >> 1; if (batch_at(batch, m, wide) < (i64)gr) lo = m + 1; else hi = m; }
    int s = lo;
    lo = s; hi = N_NODES;
    while (lo < hi) { int m = (lo + hi) >> 1; if (batch_at(batch, m, wide) < (i64)(gr + 1)) lo = m + 1; else hi = m; }
    float cnt = (float)(lo - s);

    __shared__ float st[HID];
    __shared__ float sg[HID];
    __shared__ float r0[HID], r1[HID];
    st[c] = gsum[gr * HID + c];
    __syncthreads();
    float v = 0.f;
#pragma unroll 8
    for (int k = 0; k < HID; k++) v += st[k] * loadf(W2, (size_t)k * HID + c, ff);
    sg[c] = v / fmaxf(cnt, 1.0f) + loadf(b2, c, ff);
    __syncthreads();
    float acc = loadf(bm1, c, ff);
#pragma unroll 8
    for (int k = 0; k < HID; k++) acc += sg[k] * loadf(Wm1, k * HID + c, ff);
    float hid = fmaxf(acc, 0.f);
    r0[c] = hid * loadf(Wm2, c * OUT_C + 0, ff);
    r1[c] = hid * loadf(Wm2, c * OUT_C + 1, ff);
    __syncthreads();
    for (int off = 64; off > 0; off >>= 1) {
        if (c < off) { r0[c] += r0[c + off]; r1[c] += r1[c + off]; }
        __syncthreads();
    }
    if (c == 0) {
        out[gr * OUT_C + 0] = r0[0] + loadf(bm2, 0, ff);
        out[gr * OUT_C + 1] = r1[0] + loadf(bm2, 1, ff);
    }
}

// ---------------- launch ----------------

extern "C" void kernel_launch(void* const* d_in, const int* in_sizes, int n_in,
                              void* d_out, int out_size, void* d_ws, size_t ws_size,
                              hipStream_t stream) {
    const void* x     = d_in[0];
    const void* ei    = d_in[1];
    const void* batch = d_in[2];
    const void* W1  = d_in[3];
    const void* b1  = d_in[4];
    const void* W2  = d_in[5];
    const void* b2  = d_in[6];
    const void* Wm1 = d_in[7];
    const void* bm1 = d_in[8];
    const void* Wm2 = d_in[9];
    const void* bm2 = d_in[10];

    char* p = (char*)d_ws;
    auto alloc = [&](size_t bytes) {
        char* r = p;
        p += (bytes + 255) & ~(size_t)255;
        return r;
    };
    int*    iflag  = (int*)alloc(4);
    int*    fflag  = (int*)alloc(4);
    int*    bcnt   = (int*)alloc(NBUCK * 4);
    uint2*  bmem   = (uint2*)alloc((size_t)NBUCK * BCAP * 8);
    float*  dinv   = (float*)alloc(N_NODES * 4);
    int*    offs   = (int*)alloc((N_NODES + 1) * 4);
    int*    csr    = (int*)alloc(N_EDGES * 4);
    ushort* Wt1    = (ushort*)alloc(IN_C * HID * 2);
    float*  WT     = (float*)alloc((size_t)N_NODES * N_GRAPHS * 4);
    ushort* Y1     = (ushort*)alloc((size_t)N_NODES * IN_C * 2);
    ushort* h1s    = (ushort*)alloc((size_t)N_NODES * HID * 2);
    float*  gbuf   = (float*)alloc(N_GRAPHS * HID * 4);

    k_init<<<1024, 256, 0, stream>>>(
        (const uint*)batch, (const uint*)x, bcnt, gbuf, WT, iflag, fflag);
    k_binA<<<(N_EDGES + ECH - 1) / ECH, 1024, 0, stream>>>(
        ei, iflag, fflag, W1, Wt1, bcnt, bmem);
    k_binB<<<NBUCK, 1024, 0, stream>>>(bmem, bcnt, x, batch, iflag, fflag,
                                       offs, csr, dinv, WT, Y1);

    // fused layer 1: h1s = relu((dinv*(gather Y1 + self))@W1 + b1) * dinv
    k_l1<<<(N_NODES + 63) / 64, 256, 0, stream>>>(Y1, dinv, offs, csr, Wt1, fflag, b1, h1s);
    // pooled layer 2: gsum = t = WT^T @ h1s  (no gather; @W2 deferred to MLP)
    k_pool2<<<(N_NODES + PCH - 1) / PCH, 256, 0, stream>>>(WT, h1s, gbuf);

    k_mlp<<<N_GRAPHS, HID, 0, stream>>>(gbuf, batch, iflag, W2, b2, Wm1, bm1, Wm2, bm2, fflag, (float*)d_out);
}

// Round 4
// 204.404 us; speedup vs baseline: 1.5716x; 1.5716x over previous
//
#include <hip/hip_runtime.h>
#include <stdint.h>

#define N_NODES 50000
#define N_EDGES 800000
#define IN_C 64
#define HID 128
#define OUT_C 2
#define N_GRAPHS 64
#define NBUCK 196                    // ceil(N_NODES/256) buckets of 256 nodes
#define BCAP 6144                    // bucket capacity (mean 4096, sd ~64)
#define ECH 4096                     // edges per phase-A block

typedef long long i64;
typedef __attribute__((ext_vector_type(8))) short bf8;    // 8 bf16 = 4 VGPRs
typedef __attribute__((ext_vector_type(4))) float f32x4;  // MFMA C/D frag

__device__ __forceinline__ float bf2f(ushort h) {
    return __uint_as_float(((uint)h) << 16);
}
__device__ __forceinline__ ushort f2bf(float f) {
    uint x = __float_as_uint(f);
    uint r = x + 0x7fffu + ((x >> 16) & 1u);   // RNE
    return (ushort)(r >> 16);
}
__device__ __forceinline__ float loadf(const void* p, size_t i, int bf) {
    return bf ? bf2f(((const ushort*)p)[i]) : ((const float*)p)[i];
}
__device__ __forceinline__ int clampi(int v, int lo, int hi) {
    return min(max(v, lo), hi);
}

__device__ __forceinline__ int edge_src(const void* ei, int e, int wide) {
    return wide ? (int)((const i64*)ei)[e] : ((const int*)ei)[e];
}
__device__ __forceinline__ int edge_dst(const void* ei, int e, int wide) {
    return wide ? (int)((const i64*)ei)[N_EDGES + e] : ((const int*)ei)[N_EDGES + e];
}
__device__ __forceinline__ i64 batch_at(const void* b, int i, int wide) {
    return wide ? ((const i64*)b)[i] : (i64)((const int*)b)[i];
}

__device__ __forceinline__ void bacc4(float* a, uint2 u) {
    a[0] += bf2f((ushort)(u.x & 0xffffu)); a[1] += bf2f((ushort)(u.x >> 16));
    a[2] += bf2f((ushort)(u.y & 0xffffu)); a[3] += bf2f((ushort)(u.y >> 16));
}
__device__ __forceinline__ uint pk2(float lo, float hi) {
    return ((uint)f2bf(hi) << 16) | (uint)f2bf(lo);
}

// ---- init: zero bcnt/gbuf; block 0 also runs the dtype probes ----
__global__ __launch_bounds__(256) void k_init(const uint* __restrict__ braw,
                                              const uint* __restrict__ xraw,
                                              int* __restrict__ bcnt,
                                              float* __restrict__ gbuf,
                                              int* __restrict__ iflag,
                                              int* __restrict__ fflag) {
    int i = blockIdx.x * blockDim.x + threadIdx.x;
    if (i < N_GRAPHS * HID) gbuf[i] = 0.f;
    if (i < NBUCK) bcnt[i] = 0;
    if (blockIdx.x == 0) {
        __shared__ uint si[128];
        __shared__ int sf[256];
        int t = threadIdx.x;
        if (t < 128) si[t] = (t < 100) ? braw[25001 + 2 * t] : 0u;
        uint e = (xraw[t] >> 7) & 0xFFu;
        sf[t] = (e >= 100u && e <= 140u) ? 1 : 0;
        __syncthreads();
        for (int off = 128; off > 0; off >>= 1) {
            if (t < off) {
                sf[t] += sf[t + off];
                if (off <= 64 && t < 64) si[t] |= si[t + off];
            }
            __syncthreads();
        }
        if (t == 0) {
            *iflag = (si[0] == 0u) ? 1 : 0;   // 1 = int64, 0 = int32
            *fflag = (sf[0] >= 192) ? 1 : 0;  // 1 = bf16,  0 = f32
        }
    }
}

// ---- phase A: bin edges by dst>>8 via LDS-sorted staging; contiguous runs.
// 1024 threads/block. Threads t<256 of blocks 0..95 also transpose W1/W2. ----
__global__ __launch_bounds__(1024) void k_binA(const void* __restrict__ ei,
                                               const int* __restrict__ iflag,
                                               const int* __restrict__ fflag,
                                               const void* __restrict__ W1,
                                               const void* __restrict__ W2,
                                               ushort* __restrict__ Wt1,
                                               ushort* __restrict__ Wt2,
                                               int* __restrict__ bcnt,
                                               uint2* __restrict__ bmem) {
    int t = threadIdx.x;
    if (t < 256 && blockIdx.x < (IN_C * HID + HID * HID) / 256) {
        int ff = *fflag;
        int idx = blockIdx.x * 256 + t;
        if (idx < IN_C * HID) {
            int k = idx >> 7, n = idx & 127;
            Wt1[n * IN_C + k] = f2bf(loadf(W1, idx, ff));
        } else {
            int j = idx - IN_C * HID;
            int k = j >> 7, n = j & 127;
            Wt2[n * HID + k] = f2bf(loadf(W2, j, ff));
        }
    }
    int wide = *iflag;
    __shared__ int cnt[NBUCK];
    __shared__ int obase[NBUCK];
    __shared__ int run[NBUCK];
    __shared__ int gbase[NBUCK];
    __shared__ int sc[256];
    __shared__ uint2 stage[ECH];
    int e0 = blockIdx.x * ECH;
    int m = min(ECH, N_EDGES - e0);
    for (int i = t; i < NBUCK; i += 1024) cnt[i] = 0;
    __syncthreads();
    for (int i = t; i < m; i += 1024) {
        int d = edge_dst(ei, e0 + i, wide);
        atomicAdd(&cnt[d >> 8], 1);
    }
    __syncthreads();
    int cv = (t < NBUCK) ? cnt[t] : 0;
    if (t < 256) sc[t] = cv;
    __syncthreads();
    for (int off = 1; off < 256; off <<= 1) {
        int v = (t >= off && t < 256) ? sc[t - off] : 0;
        __syncthreads();
        if (t < 256) sc[t] += v;
        __syncthreads();
    }
    if (t < NBUCK) {
        int ex = sc[t] - cv;
        obase[t] = ex;
        run[t] = ex;
        gbase[t] = (cv > 0) ? atomicAdd(&bcnt[t], cv) : 0;
    }
    __syncthreads();
    for (int i = t; i < m; i += 1024) {
        int s = edge_src(ei, e0 + i, wide);
        int d = edge_dst(ei, e0 + i, wide);
        int slot = atomicAdd(&run[d >> 8], 1);
        uint2 pr; pr.x = (uint)s; pr.y = (uint)d;
        stage[slot] = pr;
    }
    __syncthreads();
    for (int i = t; i < m; i += 1024) {
        uint2 pr = stage[i];
        int b = (int)(pr.y >> 8);
        int pos = gbase[b] + (i - obase[b]);
        if (pos < BCAP) bmem[(size_t)b * BCAP + pos] = pr;
    }
}

// ---- phase B: per-bucket LDS counting-sort -> offs/csr/dinv (coalesced),
// self-scans bcnt, writes Y1g = bf16(dinv * x) in GROUP-MAJOR [2][N][32]
// layout (each group a contiguous 3.2 MB region for L2 residency). ----
__global__ __launch_bounds__(1024) void k_binB(const uint2* __restrict__ bmem,
                                               const int* __restrict__ bcnt,
                                               const void* __restrict__ x,
                                               const int* __restrict__ fflag,
                                               int* __restrict__ offs,
                                               int* __restrict__ csr,
                                               float* __restrict__ dinv,
                                               ushort* __restrict__ Y1) {
    int b = blockIdx.x;
    int t = threadIdx.x;
    int node0 = b << 8;
    __shared__ int sc[256];
    __shared__ int degl[256];
    __shared__ int run[256];
    __shared__ float sdinv[256];
    __shared__ int sbase, scnt;
    __shared__ int stage[BCAP];
    int v = (t < NBUCK) ? bcnt[t] : 0;
    if (t < 256) sc[t] = v;
    __syncthreads();
    for (int off = 1; off < 256; off <<= 1) {
        int u = (t >= off && t < 256) ? sc[t - off] : 0;
        __syncthreads();
        if (t < 256) sc[t] += u;
        __syncthreads();
    }
    if (t == b) {
        int c = clampi(v, 0, BCAP);
        scnt = c;
        sbase = clampi(sc[t] - v, 0, N_EDGES - c);
    }
    if (t < 256) degl[t] = 0;
    __syncthreads();
    int cnt = scnt;
    int base = sbase;
    for (int i = t; i < cnt; i += 1024) {
        uint2 pr = bmem[(size_t)b * BCAP + i];
        atomicAdd(&degl[pr.y & 255], 1);
    }
    __syncthreads();
    int dv = (t < 256) ? degl[t] : 0;
    if (t < 256) sc[t] = dv;
    __syncthreads();
    for (int off = 1; off < 256; off <<= 1) {
        int u = (t >= off && t < 256) ? sc[t - off] : 0;
        __syncthreads();
        if (t < 256) sc[t] += u;
        __syncthreads();
    }
    if (t < 256) {
        int ex = sc[t] - dv;
        run[t] = ex;
        float di = rsqrtf((float)(dv + 1));
        sdinv[t] = di;
        int n = node0 + t;
        if (n < N_NODES) { offs[n] = base + ex; dinv[n] = di; }
    }
    if (b == 0 && t == 0) offs[N_NODES] = N_EDGES;
    __syncthreads();
    for (int i = t; i < cnt; i += 1024) {
        uint2 pr = bmem[(size_t)b * BCAP + i];
        int slot = atomicAdd(&run[pr.y & 255], 1);
        stage[clampi(slot, 0, BCAP - 1)] = (int)pr.x;
    }
    __syncthreads();
    for (int i = t; i < cnt; i += 1024) csr[base + i] = stage[i];
    int ff = *fflag;
    for (int idx = t; idx < 256 * (IN_C / 4); idx += 1024) {
        int nl = idx >> 4, c4 = (idx & 15) * 4;
        int nn = node0 + nl;
        if (nn < N_NODES) {
            float x0, x1, x2, x3;
            if (ff) {
                ushort4 u = *(const ushort4*)((const ushort*)x + (size_t)nn * IN_C + c4);
                x0 = bf2f(u.x); x1 = bf2f(u.y); x2 = bf2f(u.z); x3 = bf2f(u.w);
            } else {
                float4 vv = *(const float4*)((const float*)x + (size_t)nn * IN_C + c4);
                x0 = vv.x; x1 = vv.y; x2 = vv.z; x3 = vv.w;
            }
            float di = sdinv[nl];
            ushort4 o;
            o.x = f2bf(x0 * di); o.y = f2bf(x1 * di);
            o.z = f2bf(x2 * di); o.w = f2bf(x3 * di);
            int g = c4 >> 5;     // group-major write
            *(ushort4*)(Y1 + ((size_t)g * N_NODES + nn) * 32 + (c4 & 31)) = o;
        }
    }
}

// ---- R20: channel-grouped gather. Group-major src/out [(1<<SHIFT)][N][32].
// group = blockIdx & mask: with XCD round-robin (xcd = blk % 8) each XCD
// touches exactly ONE group's contiguous 3.2 MB region -> L2-resident,
// so the ~16x re-reads become L2 hits instead of L3 misses.
// 8 lanes/node, uint2 (8 B) loads, 8-edge unroll. ----
template <int SHIFT>
__global__ __launch_bounds__(256) void k_aggS(const ushort* __restrict__ src,
                                              const float* __restrict__ dinv,
                                              const int* __restrict__ offs,
                                              const int* __restrict__ csr,
                                              ushort* __restrict__ out) {
    int g = blockIdx.x & ((1 << SHIFT) - 1);
    int chunk = blockIdx.x >> SHIFT;
    int n = (chunk * 256 + (int)threadIdx.x) >> 3;
    int lane = threadIdx.x & 7;
    if (n >= N_NODES) return;
    const uint2* s2 = (const uint2*)(src + (size_t)g * N_NODES * 32);
    size_t rb = (size_t)n * 8 + lane;
    float a[4];
    {
        uint2 su = s2[rb];                     // self contribution
        a[0] = bf2f((ushort)(su.x & 0xffffu)); a[1] = bf2f((ushort)(su.x >> 16));
        a[2] = bf2f((ushort)(su.y & 0xffffu)); a[3] = bf2f((ushort)(su.y >> 16));
    }
    int s = offs[n];
    int e = min(offs[n + 1], s + 4096);        // poison-replay guard
    int i = s;
    for (; i + 8 <= e; i += 8) {
        uint2 u[8];
#pragma unroll
        for (int k = 0; k < 8; k++)
            u[k] = s2[(size_t)csr[i + k] * 8 + lane];
#pragma unroll
        for (int k = 0; k < 8; k++) bacc4(a, u[k]);
    }
    for (; i < e; i++) bacc4(a, s2[(size_t)csr[i] * 8 + lane]);
    float dv = dinv[n];
    uint2 o;
    o.x = pk2(a[0] * dv, a[1] * dv);
    o.y = pk2(a[2] * dv, a[3] * dv);
    ((uint2*)(out + (size_t)g * N_NODES * 32))[rb] = o;
}

// ------- MFMA GEMM layer 1: h1g = bf16(relu(Mg@W1 + b1) * dinv) ------------
// A and out are group-major [(K/32)][N][32] / [4][N][32].
template <int K>
__global__ __launch_bounds__(256) void k_gemm_f(const ushort* __restrict__ A,
                                                const ushort* __restrict__ Wt,
                                                const int* __restrict__ fflag,
                                                const float* __restrict__ dinv,
                                                const void* __restrict__ bias,
                                                ushort* __restrict__ out) {
    int ff = *fflag;
    int wave = threadIdx.x >> 6;
    int lane = threadIdx.x & 63;
    int m16 = lane & 15;
    int q = lane >> 4;
    int rowbase = blockIdx.x * 64 + wave * 16;
    int arow = min(rowbase + m16, N_NODES - 1);

    f32x4 acc[8];
#pragma unroll
    for (int t = 0; t < 8; t++) acc[t] = (f32x4){0.f, 0.f, 0.f, 0.f};
#pragma unroll
    for (int kc = 0; kc < K; kc += 32) {
        bf8 a = *(const bf8*)(A + ((size_t)(kc >> 5) * N_NODES + arow) * 32 + q * 8);
#pragma unroll
        for (int t = 0; t < 8; t++) {
            bf8 b = *(const bf8*)(Wt + (size_t)(t * 16 + m16) * K + kc + q * 8);
            acc[t] = __builtin_amdgcn_mfma_f32_16x16x32_bf16(a, b, acc[t], 0, 0, 0);
        }
    }
    float dv[4];
    int rowok[4];
#pragma unroll
    for (int r = 0; r < 4; r++) {
        int row = rowbase + q * 4 + r;
        rowok[r] = (row < N_NODES);
        dv[r] = rowok[r] ? dinv[row] : 1.f;
    }
#pragma unroll
    for (int t = 0; t < 8; t++) {
        int col = t * 16 + m16;
        float bv = loadf(bias, col, ff);
        ushort* og = out + (size_t)(col >> 5) * N_NODES * 32 + (col & 31);
#pragma unroll
        for (int r = 0; r < 4; r++) {
            int row = rowbase + q * 4 + r;
            if (rowok[r]) {
                float v = fmaxf(acc[t][r] + bv, 0.f) * dv[r];
                og[(size_t)row * 32] = f2bf(v);
            }
        }
    }
}

// ------- MFMA GEMM layer 2 + fused mean-pool (bias deferred to MLP) --------
// A is group-major [4][N][32].
__global__ __launch_bounds__(256) void k_gemm_pool(const ushort* __restrict__ A,
                                                   const ushort* __restrict__ Wt,
                                                   const void* __restrict__ batch,
                                                   const int* __restrict__ iflag,
                                                   float* __restrict__ gsum) {
    const int K = HID;
    int wide = *iflag;
    int tid = threadIdx.x;
    int wave = tid >> 6;
    int lane = tid & 63;
    int m16 = lane & 15;
    int q = lane >> 4;
    int rowbase = blockIdx.x * 64 + wave * 16;
    int arow = min(rowbase + m16, N_NODES - 1);

    __shared__ float sacc[64][HID];
    __shared__ int sbg[64];

    if (tid < 64) {
        int n = blockIdx.x * 64 + tid;
        int g = (n < N_NODES) ? (int)batch_at(batch, n, wide) : -1;
        sbg[tid] = (g < 0 || g >= N_GRAPHS) ? -1 : g;
    }
    f32x4 acc[8];
#pragma unroll
    for (int t = 0; t < 8; t++) acc[t] = (f32x4){0.f, 0.f, 0.f, 0.f};
#pragma unroll
    for (int kc = 0; kc < K; kc += 32) {
        bf8 a = *(const bf8*)(A + ((size_t)(kc >> 5) * N_NODES + arow) * 32 + q * 8);
#pragma unroll
        for (int t = 0; t < 8; t++) {
            bf8 b = *(const bf8*)(Wt + (size_t)(t * 16 + m16) * K + kc + q * 8);
            acc[t] = __builtin_amdgcn_mfma_f32_16x16x32_bf16(a, b, acc[t], 0, 0, 0);
        }
    }
#pragma unroll
    for (int t = 0; t < 8; t++) {
        int col = t * 16 + m16;
#pragma unroll
        for (int r = 0; r < 4; r++) {
            int rl = wave * 16 + q * 4 + r;
            int row = rowbase + q * 4 + r;
            sacc[rl][col] = (row < N_NODES) ? acc[t][r] : 0.f;
        }
    }
    __syncthreads();
    int col = tid & 127;
    int half = tid >> 7;
    int gcur = -1;
    float a = 0.f;
    for (int r = half * 32; r < half * 32 + 32; r++) {
        int g = sbg[r];
        if (g != gcur) {
            if (gcur >= 0) atomicAdd(&gsum[gcur * HID + col], a);
            a = 0.f;
            gcur = g;
        }
        a += sacc[r][col];
    }
    if (gcur >= 0) atomicAdd(&gsum[gcur * HID + col], a);
}

// -------- MLP head: out = relu((gsum/cnt + b2)@Wm1+bm1)@Wm2 + bm2 ; f32 -----
__global__ void k_mlp(const float* __restrict__ gsum, const void* __restrict__ batch,
                      const int* __restrict__ iflag, const void* __restrict__ b2,
                      const void* __restrict__ Wm1, const void* __restrict__ bm1,
                      const void* __restrict__ Wm2, const void* __restrict__ bm2,
                      const int* __restrict__ fflag, float* __restrict__ out) {
    int ff = *fflag;
    int wide = *iflag;
    int gr = blockIdx.x;
    int c = threadIdx.x;
    int lo = 0, hi = N_NODES;
    while (lo < hi) { int m = (lo + hi) >> 1; if (batch_at(batch, m, wide) < (i64)gr) lo = m + 1; else hi = m; }
    int s = lo;
    lo = s; hi = N_NODES;
    while (lo < hi) { int m = (lo + hi) >> 1; if (batch_at(batch, m, wide) < (i64)(gr + 1)) lo = m + 1; else hi = m; }
    float cnt = (float)(lo - s);

    __shared__ float sg[HID];
    __shared__ float r0[HID], r1[HID];
    sg[c] = gsum[gr * HID + c] / fmaxf(cnt, 1.0f) + loadf(b2, c, ff);
    __syncthreads();
    float acc = loadf(bm1, c, ff);
#pragma unroll 8
    for (int k = 0; k < HID; k++) acc += sg[k] * loadf(Wm1, k * HID + c, ff);
    float hid = fmaxf(acc, 0.f);
    r0[c] = hid * loadf(Wm2, c * OUT_C + 0, ff);
    r1[c] = hid * loadf(Wm2, c * OUT_C + 1, ff);
    __syncthreads();
    for (int off = 64; off > 0; off >>= 1) {
        if (c < off) { r0[c] += r0[c + off]; r1[c] += r1[c + off]; }
        __syncthreads();
    }
    if (c == 0) {
        out[gr * OUT_C + 0] = r0[0] + loadf(bm2, 0, ff);
        out[gr * OUT_C + 1] = r1[0] + loadf(bm2, 1, ff);
    }
}

// ---------------- launch ----------------

extern "C" void kernel_launch(void* const* d_in, const int* in_sizes, int n_in,
                              void* d_out, int out_size, void* d_ws, size_t ws_size,
                              hipStream_t stream) {
    const void* x     = d_in[0];
    const void* ei    = d_in[1];
    const void* batch = d_in[2];
    const void* W1  = d_in[3];
    const void* b1  = d_in[4];
    const void* W2  = d_in[5];
    const void* b2  = d_in[6];
    const void* Wm1 = d_in[7];
    const void* bm1 = d_in[8];
    const void* Wm2 = d_in[9];
    const void* bm2 = d_in[10];

    char* p = (char*)d_ws;
    auto alloc = [&](size_t bytes) {
        char* r = p;
        p += (bytes + 255) & ~(size_t)255;
        return r;
    };
    int*    iflag  = (int*)alloc(4);
    int*    fflag  = (int*)alloc(4);
    int*    bcnt   = (int*)alloc(NBUCK * 4);
    uint2*  bmem   = (uint2*)alloc((size_t)NBUCK * BCAP * 8);
    float*  dinv   = (float*)alloc(N_NODES * 4);
    int*    offs   = (int*)alloc((N_NODES + 1) * 4);
    int*    csr    = (int*)alloc(N_EDGES * 4);
    ushort* Wt1    = (ushort*)alloc(IN_C * HID * 2);
    ushort* Wt2    = (ushort*)alloc(HID * HID * 2);
    ushort* Y1g    = (ushort*)alloc((size_t)N_NODES * IN_C * 2);   // [2][N][32]
    ushort* Mg     = (ushort*)alloc((size_t)N_NODES * IN_C * 2);   // [2][N][32]
    ushort* h1g    = (ushort*)alloc((size_t)N_NODES * HID * 2);    // [4][N][32]
    ushort* N2g    = (ushort*)alloc((size_t)N_NODES * HID * 2);    // [4][N][32]
    float*  gbuf   = (float*)alloc(N_GRAPHS * HID * 4);

    k_init<<<(N_GRAPHS * HID + 255) / 256, 256, 0, stream>>>(
        (const uint*)batch, (const uint*)x, bcnt, gbuf, iflag, fflag);
    k_binA<<<(N_EDGES + ECH - 1) / ECH, 1024, 0, stream>>>(
        ei, iflag, fflag, W1, W2, Wt1, Wt2, bcnt, bmem);
    k_binB<<<NBUCK, 1024, 0, stream>>>(bmem, bcnt, x, fflag, offs, csr, dinv, Y1g);

    int cpg = (N_NODES * 8 + 255) / 256;   // chunks per group (1563)
    // layer 1: Mg = dinv*(gather Y1g + self), 2 channel groups (XCD-resident)
    k_aggS<1><<<cpg * 2, 256, 0, stream>>>(Y1g, dinv, offs, csr, Mg);
    // h1g = relu(Mg@W1 + b1)*dinv, group-major out
    k_gemm_f<IN_C><<<(N_NODES + 63) / 64, 256, 0, stream>>>(Mg, Wt1, fflag, dinv, b1, h1g);
    // layer 2: N2g = dinv*(gather h1g + self), 4 channel groups (XCD-resident)
    k_aggS<2><<<cpg * 4, 256, 0, stream>>>(h1g, dinv, offs, csr, N2g);
    // pool(N2g@W2) fused
    k_gemm_pool<<<(N_NODES + 63) / 64, 256, 0, stream>>>(N2g, Wt2, batch, iflag, gbuf);

    k_mlp<<<N_GRAPHS, HID, 0, stream>>>(gbuf, batch, iflag, b2, Wm1, bm1, Wm2, bm2, fflag, (float*)d_out);
}